// Round 2
// baseline (6583.282 us; speedup 1.0000x reference)
//
#include <hip/hip_runtime.h>
#include <hip/hip_bf16.h>
#include <math.h>

#define NF 50000
#define NFP 50048
#define NV 1024
#define NA 64
#define NSLICE 25
#define SCALE_QK 0.088388347648318447f

// ---------------- ws layout (bytes) ----------------
static const size_t OFF_K    = 0;                                   // float [NFP*128]
static const size_t OFF_V    = OFF_K   + (size_t)NFP*128*4;         // float [NFP*128]
static const size_t OFF_P    = OFF_V   + (size_t)NFP*128*4;         // bf16  [NV*NFP]
static const size_t OFF_H    = OFF_P   + (size_t)NV*NFP*2;          // float [NV*128]
static const size_t OFF_Q    = OFF_H   + (size_t)NV*128*4;          // float [NV*128]
static const size_t OFF_PART = OFF_Q   + (size_t)NV*128*4;          // float [25*NV*128]
static const size_t OFF_ACC  = OFF_PART+ (size_t)NSLICE*NV*128*4;   // float Z,Zl,Yp,Yl [4*1024] + avg[3*1024]
static const size_t OFF_CNT  = OFF_ACC + 28672;                     // float [64]
static const size_t OFF_CTR  = OFF_CNT + 256;                       // uint  [16]

// ---------------- helpers ----------------
__device__ __forceinline__ float bflo(unsigned w){ union{unsigned u;float f;}c; c.u=w<<16; return c.f; }
__device__ __forceinline__ float bfhi(unsigned w){ union{unsigned u;float f;}c; c.u=w&0xffff0000u; return c.f; }
__device__ __forceinline__ unsigned short f2bf(float x){ __hip_bfloat16 b=__float2bfloat16(x); return *(unsigned short*)&b; }
__device__ __forceinline__ float geluf(float x){ return 0.5f*x*(1.0f+erff(x*0.70710678118654752f)); }
__device__ __forceinline__ float sigmf(float x){ return 1.0f/(1.0f+__expf(-x)); }

__device__ __forceinline__ void gridbar(unsigned* ctr, unsigned target){
  __syncthreads();
  if (threadIdx.x==0){
    __hip_atomic_fetch_add(ctr, 1u, __ATOMIC_ACQ_REL, __HIP_MEMORY_SCOPE_AGENT);
    while (__hip_atomic_load(ctr, __ATOMIC_ACQUIRE, __HIP_MEMORY_SCOPE_AGENT) < target)
      __builtin_amdgcn_s_sleep(1);
  }
  __syncthreads();
}

// ---------------- cnt per atom ----------------
__global__ __launch_bounds__(256) void cnt_kern(const int* __restrict__ cm, float* __restrict__ cntf){
  __shared__ int sd[256];
  const int a=blockIdx.x, t=threadIdx.x;
  int s=0;
  for (int i=t;i<NV;i+=256) s+=cm[a*NV+i];
  sd[t]=s; __syncthreads();
  for (int o=128;o>0;o>>=1){ if(t<o) sd[t]+=sd[t+o]; __syncthreads(); }
  if (t==0) cntf[a]=(float)sd[0];
}

// ---------------- K/V projection: (NFP x 128) = fe @ W + b ----------------
__global__ __launch_bounds__(256)
void kvproj_kern(const float* __restrict__ fe,
                 const float* __restrict__ Wk, const float* __restrict__ bk,
                 const float* __restrict__ Wv, const float* __restrict__ bv,
                 float* __restrict__ Kout, float* __restrict__ Vout){
  __shared__ float As[32][68];
  __shared__ float Bs[32][132];
  const int t=threadIdx.x;
  const int f0=blockIdx.x*64;
  const float* W  = blockIdx.y ? Wv : Wk;
  const float* bb = blockIdx.y ? bv : bk;
  float* Out      = blockIdx.y ? Vout : Kout;
  float acc[4][8];
  #pragma unroll
  for(int i=0;i<4;i++){ for(int j=0;j<8;j++) acc[i][j]=0.f; }
  for (int kc=0;kc<128;kc+=32){
    { const int floc=t>>2, koff=(t&3)*8; const int f=f0+floc;
      if (f<NF){
        const float* src=fe+((size_t)f<<7)+kc+koff;
        float4 a=*(const float4*)src, b=*(const float4*)(src+4);
        As[koff+0][floc]=a.x; As[koff+1][floc]=a.y; As[koff+2][floc]=a.z; As[koff+3][floc]=a.w;
        As[koff+4][floc]=b.x; As[koff+5][floc]=b.y; As[koff+6][floc]=b.z; As[koff+7][floc]=b.w;
      } else { for(int i=0;i<8;i++) As[koff+i][floc]=0.f; } }
    { const int kk=t>>3, coff=(t&7)*16;
      const float* src=W+((size_t)(kc+kk)<<7)+coff;
      float4 a=*(const float4*)src, b=*(const float4*)(src+4), c=*(const float4*)(src+8), d=*(const float4*)(src+12);
      Bs[kk][coff+0]=a.x;Bs[kk][coff+1]=a.y;Bs[kk][coff+2]=a.z;Bs[kk][coff+3]=a.w;
      Bs[kk][coff+4]=b.x;Bs[kk][coff+5]=b.y;Bs[kk][coff+6]=b.z;Bs[kk][coff+7]=b.w;
      Bs[kk][coff+8]=c.x;Bs[kk][coff+9]=c.y;Bs[kk][coff+10]=c.z;Bs[kk][coff+11]=c.w;
      Bs[kk][coff+12]=d.x;Bs[kk][coff+13]=d.y;Bs[kk][coff+14]=d.z;Bs[kk][coff+15]=d.w; }
    __syncthreads();
    const int mloc=(t&15)*4, nloc=(t>>4)*8;
    #pragma unroll
    for (int kk=0;kk<32;kk++){
      const float4 a=*(const float4*)&As[kk][mloc];
      const float4 b0=*(const float4*)&Bs[kk][nloc];
      const float4 b1=*(const float4*)&Bs[kk][nloc+4];
      const float am[4]={a.x,a.y,a.z,a.w};
      const float bn[8]={b0.x,b0.y,b0.z,b0.w,b1.x,b1.y,b1.z,b1.w};
      #pragma unroll
      for(int mi=0;mi<4;mi++){
        #pragma unroll
        for(int ni=0;ni<8;ni++) acc[mi][ni]=fmaf(am[mi],bn[ni],acc[mi][ni]);
      }
    }
    __syncthreads();
  }
  const int mloc=(t&15)*4, nloc=(t>>4)*8;
  #pragma unroll
  for(int mi=0;mi<4;mi++){
    const int f=f0+mloc+mi;
    float o[8];
    #pragma unroll
    for(int ni=0;ni<8;ni++) o[ni]=(f<NF)? (acc[mi][ni]+bb[nloc+ni]) : 0.f;
    float* dst=Out+((size_t)f<<7)+nloc;
    *(float4*)dst     = make_float4(o[0],o[1],o[2],o[3]);
    *(float4*)(dst+4) = make_float4(o[4],o[5],o[6],o[7]);
  }
}

// ---------------- q = h @ Wq + bq ----------------
__global__ __launch_bounds__(128)
void qproj_kern(const float* __restrict__ h, const float* __restrict__ Wq,
                const float* __restrict__ bq, float* __restrict__ q){
  __shared__ float hs[128];
  const int v=blockIdx.x, c=threadIdx.x;
  hs[c]=h[(v<<7)+c];
  __syncthreads();
  float acc=bq[c];
  #pragma unroll 8
  for (int k=0;k<128;k++) acc=fmaf(hs[k],Wq[(k<<7)+c],acc);
  q[(v<<7)+c]=acc;
}

// ---------------- scores: P = exp(scale*q.K^T) (bf16), + row sums ----------------
template<int FINAL>
__global__ __launch_bounds__(256)
void scores_kern(const float* __restrict__ qb, const float* __restrict__ Kb,
                 const float* __restrict__ gum, unsigned short* __restrict__ Pb,
                 float* __restrict__ accg){
  __shared__ float As[32][68];
  __shared__ float Bs[32][132];
  __shared__ float Zs[64], Zls[64], Yps[64], Yls[64];
  const int t=threadIdx.x;
  const int f0=blockIdx.x*128;
  const int v0=blockIdx.y*64;
  float acc[4][8];
  #pragma unroll
  for(int i=0;i<4;i++){ for(int j=0;j<8;j++) acc[i][j]=0.f; }
  if (t<64){ Zs[t]=0.f; if(FINAL){ Zls[t]=0.f; Yps[t]=0.f; Yls[t]=0.f; } }
  for (int kc=0;kc<128;kc+=32){
    { const int vloc=t>>2, koff=(t&3)*8;
      const float* src=qb+((size_t)(v0+vloc)<<7)+kc+koff;
      float4 a=*(const float4*)src, b=*(const float4*)(src+4);
      As[koff+0][vloc]=a.x; As[koff+1][vloc]=a.y; As[koff+2][vloc]=a.z; As[koff+3][vloc]=a.w;
      As[koff+4][vloc]=b.x; As[koff+5][vloc]=b.y; As[koff+6][vloc]=b.z; As[koff+7][vloc]=b.w; }
    { const int floc=t>>1, koff=(t&1)*16; const int f=f0+floc;
      if (f<NF){
        const float* src=Kb+((size_t)f<<7)+kc+koff;
        float4 a=*(const float4*)src, b=*(const float4*)(src+4), c=*(const float4*)(src+8), d=*(const float4*)(src+12);
        Bs[koff+0][floc]=a.x;Bs[koff+1][floc]=a.y;Bs[koff+2][floc]=a.z;Bs[koff+3][floc]=a.w;
        Bs[koff+4][floc]=b.x;Bs[koff+5][floc]=b.y;Bs[koff+6][floc]=b.z;Bs[koff+7][floc]=b.w;
        Bs[koff+8][floc]=c.x;Bs[koff+9][floc]=c.y;Bs[koff+10][floc]=c.z;Bs[koff+11][floc]=c.w;
        Bs[koff+12][floc]=d.x;Bs[koff+13][floc]=d.y;Bs[koff+14][floc]=d.z;Bs[koff+15][floc]=d.w;
      } else { for(int i=0;i<16;i++) Bs[koff+i][floc]=0.f; } }
    __syncthreads();
    const int mloc=(t&15)*4, nloc=(t>>4)*8;
    #pragma unroll
    for (int kk=0;kk<32;kk++){
      const float4 a=*(const float4*)&As[kk][mloc];
      const float4 b0=*(const float4*)&Bs[kk][nloc];
      const float4 b1=*(const float4*)&Bs[kk][nloc+4];
      const float am[4]={a.x,a.y,a.z,a.w};
      const float bn[8]={b0.x,b0.y,b0.z,b0.w,b1.x,b1.y,b1.z,b1.w};
      #pragma unroll
      for(int mi=0;mi<4;mi++){
        #pragma unroll
        for(int ni=0;ni<8;ni++) acc[mi][ni]=fmaf(am[mi],bn[ni],acc[mi][ni]);
      }
    }
    __syncthreads();
  }
  const int mloc=(t&15)*4, nloc=(t>>4)*8;
  #pragma unroll
  for(int mi=0;mi<4;mi++){
    const int v=v0+mloc+mi;
    float zp=0.f, zl=0.f, yp=0.f, yl=0.f;
    float uu[8];
    if (FINAL){
      const int fbase=f0+nloc;
      if (fbase+8<=NF){
        const float* gsrc=gum+(size_t)v*NF+fbase;
        float4 g0=*(const float4*)gsrc, g1=*(const float4*)(gsrc+4);
        uu[0]=g0.x;uu[1]=g0.y;uu[2]=g0.z;uu[3]=g0.w;uu[4]=g1.x;uu[5]=g1.y;uu[6]=g1.z;uu[7]=g1.w;
      } else {
        for(int i=0;i<8;i++){ int f=fbase+i; uu[i]=(f<NF)? gum[(size_t)v*NF+f] : 0.5f; }
      }
    }
    unsigned short pr[8];
    #pragma unroll
    for(int ni=0;ni<8;ni++){
      const int f=f0+nloc+ni;
      const float s=acc[mi][ni]*SCALE_QK;
      float pv_=0.f;
      if (f<NF){
        const float ep=__expf(s);
        if (FINAL){
          const float g=-__logf(-__logf(uu[ni]));
          const float el=__expf(2.0f*(s+g));
          pv_=el; zl+=el; yl+=el*s; zp+=ep; yp+=ep*s;
        } else { pv_=ep; zp+=ep; }
      }
      pr[ni]=f2bf(pv_);
    }
    uint4 pk;
    pk.x=(unsigned)pr[0]|((unsigned)pr[1]<<16);
    pk.y=(unsigned)pr[2]|((unsigned)pr[3]<<16);
    pk.z=(unsigned)pr[4]|((unsigned)pr[5]<<16);
    pk.w=(unsigned)pr[6]|((unsigned)pr[7]<<16);
    *(uint4*)(Pb+(size_t)v*NFP+f0+nloc)=pk;
    atomicAdd(&Zs[mloc+mi],zp);
    if (FINAL){ atomicAdd(&Zls[mloc+mi],zl); atomicAdd(&Yps[mloc+mi],yp); atomicAdd(&Yls[mloc+mi],yl); }
  }
  __syncthreads();
  if (t<64){
    atomicAdd(&accg[v0+t],Zs[t]);
    if (FINAL){
      atomicAdd(&accg[1024+v0+t],Zls[t]);
      atomicAdd(&accg[2048+v0+t],Yps[t]);
      atomicAdd(&accg[3072+v0+t],Yls[t]);
    }
  }
}

// ---------------- PV: partial[slice] = P_slice @ V_slice ----------------
__global__ __launch_bounds__(256)
void pv_kern(const unsigned short* __restrict__ Pb, const float* __restrict__ Vb,
             float* __restrict__ part){
  __shared__ float As[32][68];
  __shared__ float Bs[32][132];
  const int t=threadIdx.x;
  const int slice=blockIdx.x;
  const int v0=blockIdx.y*64;
  const int fbeg=slice*2048;
  const int fend=min(fbeg+2048,(int)NFP);
  float acc[4][8];
  #pragma unroll
  for(int i=0;i<4;i++){ for(int j=0;j<8;j++) acc[i][j]=0.f; }
  for (int fc=fbeg; fc<fend; fc+=32){
    { const int vloc=t>>2, koff=(t&3)*8;
      const unsigned short* src=Pb+(size_t)(v0+vloc)*NFP+fc+koff;
      uint4 r=*(const uint4*)src;
      As[koff+0][vloc]=bflo(r.x); As[koff+1][vloc]=bfhi(r.x);
      As[koff+2][vloc]=bflo(r.y); As[koff+3][vloc]=bfhi(r.y);
      As[koff+4][vloc]=bflo(r.z); As[koff+5][vloc]=bfhi(r.z);
      As[koff+6][vloc]=bflo(r.w); As[koff+7][vloc]=bfhi(r.w); }
    { const int kk=t>>3, doff=(t&7)*16;
      const float* src=Vb+((size_t)(fc+kk)<<7)+doff;
      float4 a=*(const float4*)src, b=*(const float4*)(src+4), c=*(const float4*)(src+8), d=*(const float4*)(src+12);
      Bs[kk][doff+0]=a.x;Bs[kk][doff+1]=a.y;Bs[kk][doff+2]=a.z;Bs[kk][doff+3]=a.w;
      Bs[kk][doff+4]=b.x;Bs[kk][doff+5]=b.y;Bs[kk][doff+6]=b.z;Bs[kk][doff+7]=b.w;
      Bs[kk][doff+8]=c.x;Bs[kk][doff+9]=c.y;Bs[kk][doff+10]=c.z;Bs[kk][doff+11]=c.w;
      Bs[kk][doff+12]=d.x;Bs[kk][doff+13]=d.y;Bs[kk][doff+14]=d.z;Bs[kk][doff+15]=d.w; }
    __syncthreads();
    const int mloc=(t&15)*4, nloc=(t>>4)*8;
    #pragma unroll
    for (int kk=0;kk<32;kk++){
      const float4 a=*(const float4*)&As[kk][mloc];
      const float4 b0=*(const float4*)&Bs[kk][nloc];
      const float4 b1=*(const float4*)&Bs[kk][nloc+4];
      const float am[4]={a.x,a.y,a.z,a.w};
      const float bn[8]={b0.x,b0.y,b0.z,b0.w,b1.x,b1.y,b1.z,b1.w};
      #pragma unroll
      for(int mi=0;mi<4;mi++){
        #pragma unroll
        for(int ni=0;ni<8;ni++) acc[mi][ni]=fmaf(am[mi],bn[ni],acc[mi][ni]);
      }
    }
    __syncthreads();
  }
  const int mloc=(t&15)*4, nloc=(t>>4)*8;
  #pragma unroll
  for(int mi=0;mi<4;mi++){
    const int v=v0+mloc+mi;
    float* dst=part+(((size_t)slice*NV+v)<<7)+nloc;
    *(float4*)dst     = make_float4(acc[mi][0],acc[mi][1],acc[mi][2],acc[mi][3]);
    *(float4*)(dst+4) = make_float4(acc[mi][4],acc[mi][5],acc[mi][6],acc[mi][7]);
  }
}

// ---------------- main-loop gate update ----------------
__global__ __launch_bounds__(256)
void gate_kern(float* __restrict__ h, const float* __restrict__ part, const float* __restrict__ Z,
               const float* __restrict__ Wm1, const float* __restrict__ bm1,
               const float* __restrict__ Wm2, const float* __restrict__ bm2){
  const int t=threadIdx.x, w=t>>6, lane=t&63;
  const int v=(blockIdx.x<<2)+w;
  const float h0=h[(v<<7)+lane], h1=h[(v<<7)+64+lane];
  const float zr=1.0f/Z[v];
  float c0=0.f,c1=0.f;
  for (int s=0;s<NSLICE;s++){
    c0+=part[(((size_t)s*NV+v)<<7)+lane];
    c1+=part[(((size_t)s*NV+v)<<7)+64+lane];
  }
  c0*=zr; c1*=zr;
  float y0=bm1[lane], y1=bm1[64+lane];
  for (int k=0;k<64;k++){ const float a=__shfl(h0,k); y0=fmaf(a,Wm1[(k<<7)+lane],y0);      y1=fmaf(a,Wm1[(k<<7)+64+lane],y1); }
  for (int k=0;k<64;k++){ const float a=__shfl(h1,k); y0=fmaf(a,Wm1[((64+k)<<7)+lane],y0); y1=fmaf(a,Wm1[((64+k)<<7)+64+lane],y1); }
  for (int k=0;k<64;k++){ const float a=__shfl(c0,k); y0=fmaf(a,Wm1[((128+k)<<7)+lane],y0);y1=fmaf(a,Wm1[((128+k)<<7)+64+lane],y1); }
  for (int k=0;k<64;k++){ const float a=__shfl(c1,k); y0=fmaf(a,Wm1[((192+k)<<7)+lane],y0);y1=fmaf(a,Wm1[((192+k)<<7)+64+lane],y1); }
  y0=geluf(y0); y1=geluf(y1);
  float z0=bm2[lane], z1=bm2[64+lane];
  for (int k=0;k<64;k++){ const float a=__shfl(y0,k); z0=fmaf(a,Wm2[(k<<7)+lane],z0);      z1=fmaf(a,Wm2[(k<<7)+64+lane],z1); }
  for (int k=0;k<64;k++){ const float a=__shfl(y1,k); z0=fmaf(a,Wm2[((64+k)<<7)+lane],z0); z1=fmaf(a,Wm2[((64+k)<<7)+64+lane],z1); }
  const float g0=sigmf(z0), g1=sigmf(z1);
  h[(v<<7)+lane]   = fmaf(g0,c0-h0,h0);
  h[(v<<7)+64+lane]= fmaf(g1,c1-h1,h1);
}

// ---------------- cooc scan (persistent, 64 blocks x 1024 thr, grid barrier per atom) ----------------
// 16 vars per block (1 var per wave). Seeds are LDS-aggregated per block then pushed
// with ONE 128-float global atomicAdd per block (8x fewer far atomics than per-var).
__global__ __launch_bounds__(1024,4)
void cooc_kern(float* __restrict__ h, const int* __restrict__ cm, const float* __restrict__ cntf,
               const float* __restrict__ Wc1, const float* __restrict__ bc1,
               const float* __restrict__ Wc2, const float* __restrict__ bc2,
               float* __restrict__ bufs, unsigned* __restrict__ ctr){
  __shared__ unsigned W1s[128*64];   // bf16 pairs (c, c+64), Wc1 rows 0..127 (h-part)
  __shared__ unsigned W2s[104*64];   // bf16 pairs, Wc2 rows 0..103 (rest from global)
  __shared__ float ypart[1024];      // 8 k-segments x 128 outputs for avg@Wc1
  __shared__ float avgs[128];
  __shared__ float yavs[128];
  __shared__ float seedb[128];
  __shared__ int   anyf;
  const int t=threadIdx.x, w=t>>6, lane=t&63;
  const int v=(blockIdx.x<<4)+w;
  const int stripe=blockIdx.x&7;
  for (int i=t;i<128*64;i+=1024){ const int k=i>>6,l=i&63;
    W1s[i]=(unsigned)f2bf(Wc1[(k<<7)+l])|(((unsigned)f2bf(Wc1[(k<<7)+64+l]))<<16); }
  for (int i=t;i<104*64;i+=1024){ const int k=i>>6,l=i&63;
    W2s[i]=(unsigned)f2bf(Wc2[(k<<7)+l])|(((unsigned)f2bf(Wc2[(k<<7)+64+l]))<<16); }
  float h0=h[(v<<7)+lane], h1=h[(v<<7)+64+lane];
  const float b10=bc1[lane], b11=bc1[64+lane];
  const float b20=bc2[lane], b21=bc2[64+lane];
  // ---- seed atom 0 (bufs pre-zeroed by host memset) ----
  if (t<128) seedb[t]=0.f;
  if (t==0) anyf=0;
  __syncthreads();
  if (cm[v]!=0){ atomicAdd(&seedb[lane],h0); atomicAdd(&seedb[64+lane],h1); if(lane==0) anyf=1; }
  __syncthreads();
  if (anyf && t<128) atomicAdd(&bufs[(stripe<<7)+t],seedb[t]);
  unsigned tgt=gridDim.x;
  gridbar(ctr,tgt); tgt+=gridDim.x;
  for (int a=0;a<NA;a++){
    const int cur=a%3, nxt=(a+1)%3, zz=(a+2)%3;
    const float cf=cntf[a];
    // ---- read striped sum -> avgs ----
    if (t<128){
      float s=0.f;
      #pragma unroll
      for (int sp=0;sp<8;sp++)
        s+=__hip_atomic_load(&bufs[(cur<<10)+(sp<<7)+t],__ATOMIC_RELAXED,__HIP_MEMORY_SCOPE_AGENT);
      avgs[t]=s/fmaxf(cf,1.0f);
    }
    if (blockIdx.x==0)
      __hip_atomic_store(&bufs[(zz<<10)+t],0.0f,__ATOMIC_RELAXED,__HIP_MEMORY_SCOPE_AGENT);
    __syncthreads();
    // ---- yavs = avgs @ Wc1[128:256,:]  (split over 8 k-segments, all 16 waves) ----
    { const int seg=t>>7, ok=t&127;
      const int kb=seg<<4;
      float s=0.f;
      #pragma unroll
      for (int j=0;j<16;j++) s=fmaf(avgs[kb+j],Wc1[((128+kb+j)<<7)+ok],s);
      ypart[(seg<<7)+ok]=s; }
    __syncthreads();
    if (t<128){
      float s=0.f;
      #pragma unroll
      for (int seg=0;seg<8;seg++) s+=ypart[(seg<<7)+t];
      yavs[t]=s;
    } else if (t<256) seedb[t-128]=0.f;
    else if (t==256) anyf=0;
    __syncthreads();
    // ---- gate update (1 var per wave) ----
    const bool act=(cm[a*NV+v]!=0)&&(cf>=2.0f);
    if (act){
      const float av0=avgs[lane], av1=avgs[64+lane];
      float y0=b10+yavs[lane], y1=b11+yavs[64+lane];
      #pragma unroll 8
      for (int k=0;k<64;k++){ const float hk=__shfl(h0,k); const unsigned wp=W1s[(k<<6)+lane];
        y0=fmaf(hk,bflo(wp),y0); y1=fmaf(hk,bfhi(wp),y1); }
      #pragma unroll 8
      for (int k=0;k<64;k++){ const float hk=__shfl(h1,k); const unsigned wp=W1s[((64+k)<<6)+lane];
        y0=fmaf(hk,bflo(wp),y0); y1=fmaf(hk,bfhi(wp),y1); }
      y0=geluf(y0); y1=geluf(y1);
      float z0=b20, z1=b21;
      #pragma unroll 8
      for (int k=0;k<64;k++){ const float yk=__shfl(y0,k); const unsigned wp=W2s[(k<<6)+lane];
        z0=fmaf(yk,bflo(wp),z0); z1=fmaf(yk,bfhi(wp),z1); }
      #pragma unroll 8
      for (int k=0;k<40;k++){ const float yk=__shfl(y1,k); const unsigned wp=W2s[((64+k)<<6)+lane];
        z0=fmaf(yk,bflo(wp),z0); z1=fmaf(yk,bfhi(wp),z1); }
      for (int k=40;k<64;k++){ const float yk=__shfl(y1,k);
        z0=fmaf(yk,Wc2[((64+k)<<7)+lane],z0); z1=fmaf(yk,Wc2[((64+k)<<7)+64+lane],z1); }
      const float g0=sigmf(z0), g1=sigmf(z1);
      h0=fmaf(g0,av0-h0,h0); h1=fmaf(g1,av1-h1,h1);
    }
    // ---- block-aggregated seed for atom a+1 ----
    if (a<NA-1){
      if (cm[(a+1)*NV+v]!=0){
        atomicAdd(&seedb[lane],h0); atomicAdd(&seedb[64+lane],h1);
        if (lane==0) anyf=1;
      }
      __syncthreads();
      if (anyf && t<128)
        atomicAdd(&bufs[(nxt<<10)+(stripe<<7)+t],seedb[t]);
      gridbar(ctr,tgt); tgt+=gridDim.x;
    }
  }
  h[(v<<7)+lane]=h0; h[(v<<7)+64+lane]=h1;
}

// ---------------- final write-out ----------------
__global__ __launch_bounds__(256)
void writeout_kern(const float* __restrict__ accg, const float* __restrict__ part,
                   float* __restrict__ out){
  const int b=blockIdx.x, t=threadIdx.x;
  const int v0=b*16;
  for (int i=t;i<16*128;i+=256){
    const int v=v0+(i>>7), d=i&127;
    float s=0.f;
    for (int sl=0;sl<NSLICE;sl++) s+=part[(((size_t)sl*NV+v)<<7)+d];
    out[1+((size_t)v<<7)+d]=s/accg[1024+v];
  }
  __shared__ float es[16], hsv[16];
  if (t<16){
    const int v=v0+t;
    const float Zp=accg[v], Zl=accg[1024+v], Yp=accg[2048+v], Yl=accg[3072+v];
    es[t]=-Yl/Zl;
    hsv[t]=-(Yp/Zp-logf(Zp));
  }
  __syncthreads();
  if (t==0){
    float a=0.f,c=0.f;
    for(int i=0;i<16;i++){ a+=es[i]; c+=hsv[i]; }
    atomicAdd(&out[0],a);
    atomicAdd(&out[1+(size_t)NV*128],c);
  }
}

// ---------------- host ----------------
extern "C" void kernel_launch(void* const* d_in, const int* in_sizes, int n_in,
                              void* d_out, int out_size, void* d_ws, size_t ws_size,
                              hipStream_t stream){
  (void)in_sizes; (void)n_in; (void)ws_size;
  const float* fe =(const float*)d_in[0];
  const float* vi =(const float*)d_in[1];
  const int*   cm =(const int*)  d_in[2];
  const float* gum=(const float*)d_in[3];
  const float* Wq =(const float*)d_in[4];  const float* bq =(const float*)d_in[5];
  const float* Wk =(const float*)d_in[6];  const float* bk =(const float*)d_in[7];
  const float* Wv =(const float*)d_in[8];  const float* bv =(const float*)d_in[9];
  const float* Wm1=(const float*)d_in[10]; const float* bm1=(const float*)d_in[11];
  const float* Wm2=(const float*)d_in[12]; const float* bm2=(const float*)d_in[13];
  const float* Wc1=(const float*)d_in[14]; const float* bc1=(const float*)d_in[15];
  const float* Wc2=(const float*)d_in[16]; const float* bc2=(const float*)d_in[17];
  float* out=(float*)d_out;
  char* w8=(char*)d_ws;
  float* Kb=(float*)(w8+OFF_K);
  float* Vb=(float*)(w8+OFF_V);
  unsigned short* Pb=(unsigned short*)(w8+OFF_P);
  float* hb=(float*)(w8+OFF_H);
  float* qb=(float*)(w8+OFF_Q);
  float* part=(float*)(w8+OFF_PART);
  float* accb=(float*)(w8+OFF_ACC);
  float* avgb=accb+4096;
  float* cntf=(float*)(w8+OFF_CNT);
  unsigned* ctrs=(unsigned*)(w8+OFF_CTR);

  hipMemsetAsync(out,0,(size_t)out_size*4,stream);
  hipMemsetAsync(ctrs,0,64,stream);
  hipMemcpyAsync(hb,vi,(size_t)NV*128*4,hipMemcpyDeviceToDevice,stream);
  cnt_kern<<<NA,256,0,stream>>>(cm,cntf);
  kvproj_kern<<<dim3(NFP/64,2),256,0,stream>>>(fe,Wk,bk,Wv,bv,Kb,Vb);

  for (int it=0; it<3; it++){
    hipMemsetAsync(accb,0,28672,stream);
    qproj_kern<<<NV,128,0,stream>>>(hb,Wq,bq,qb);
    scores_kern<0><<<dim3(NFP/128,16),256,0,stream>>>(qb,Kb,nullptr,Pb,accb);
    pv_kern<<<dim3(NSLICE,16),256,0,stream>>>(Pb,Vb,part);
    gate_kern<<<NV/4,256,0,stream>>>(hb,part,accb,Wm1,bm1,Wm2,bm2);
    cooc_kern<<<64,1024,0,stream>>>(hb,cm,cntf,Wc1,bc1,Wc2,bc2,avgb,ctrs+it);
  }

  hipMemsetAsync(accb,0,28672,stream);
  qproj_kern<<<NV,128,0,stream>>>(hb,Wq,bq,qb);
  scores_kern<1><<<dim3(NFP/128,16),256,0,stream>>>(qb,Kb,gum,Pb,accb);
  pv_kern<<<dim3(NSLICE,16),256,0,stream>>>(Pb,Vb,part);
  writeout_kern<<<64,256,0,stream>>>(accb,part,out);
}

// Round 3
// 5999.430 us; speedup vs baseline: 1.0973x; 1.0973x over previous
//
#include <hip/hip_runtime.h>
#include <hip/hip_bf16.h>
#include <math.h>

#define NF 50000
#define NFP 50048
#define NV 1024
#define NA 64
#define NSLICE 25
#define SCALE_QK 0.088388347648318447f

// ---------------- ws layout (bytes) ----------------
static const size_t OFF_K    = 0;                                   // float [NFP*128]
static const size_t OFF_V    = OFF_K   + (size_t)NFP*128*4;         // float [NFP*128]
static const size_t OFF_P    = OFF_V   + (size_t)NFP*128*4;         // bf16  [NV*NFP]
static const size_t OFF_H    = OFF_P   + (size_t)NV*NFP*2;          // float [NV*128]
static const size_t OFF_Q    = OFF_H   + (size_t)NV*128*4;          // float [NV*128]
static const size_t OFF_PART = OFF_Q   + (size_t)NV*128*4;          // float [25*NV*128]
static const size_t OFF_ACC  = OFF_PART+ (size_t)NSLICE*NV*128*4;   // float Z,Zl,Yp,Yl [4*1024] + avg[3*1024]
static const size_t OFF_CNT  = OFF_ACC + 28672;                     // float [64]
static const size_t OFF_CTR  = OFF_CNT + 256;                       // uint  [16]

// ---------------- helpers ----------------
__device__ __forceinline__ float bflo(unsigned w){ union{unsigned u;float f;}c; c.u=w<<16; return c.f; }
__device__ __forceinline__ float bfhi(unsigned w){ union{unsigned u;float f;}c; c.u=w&0xffff0000u; return c.f; }
__device__ __forceinline__ unsigned short f2bf(float x){ __hip_bfloat16 b=__float2bfloat16(x); return *(unsigned short*)&b; }
__device__ __forceinline__ float geluf(float x){ return 0.5f*x*(1.0f+erff(x*0.70710678118654752f)); }
__device__ __forceinline__ float sigmf(float x){ return 1.0f/(1.0f+__expf(-x)); }

// RELAXED grid barrier: no acquire/release -> no per-poll L2 invalidate, no
// per-arrival L2 writeback. Visibility contract: all cross-block data (bufs)
// is written via atomics (execute at L3) or agent relaxed stores, and read via
// agent relaxed atomic loads (bypass local caches). Ordering "my bufs writes
// reach L3 before my counter bump" is enforced by the s_waitcnt vmcnt(0) the
// compiler emits before s_barrier in the leading __syncthreads().
__device__ __forceinline__ void gridbar(unsigned* ctr, unsigned target){
  __syncthreads();
  if (threadIdx.x==0){
    __hip_atomic_fetch_add(ctr, 1u, __ATOMIC_RELAXED, __HIP_MEMORY_SCOPE_AGENT);
    while (__hip_atomic_load(ctr, __ATOMIC_RELAXED, __HIP_MEMORY_SCOPE_AGENT) < target)
      __builtin_amdgcn_s_sleep(1);
  }
  __syncthreads();
}

// ---------------- cnt per atom ----------------
__global__ __launch_bounds__(256) void cnt_kern(const int* __restrict__ cm, float* __restrict__ cntf){
  __shared__ int sd[256];
  const int a=blockIdx.x, t=threadIdx.x;
  int s=0;
  for (int i=t;i<NV;i+=256) s+=cm[a*NV+i];
  sd[t]=s; __syncthreads();
  for (int o=128;o>0;o>>=1){ if(t<o) sd[t]+=sd[t+o]; __syncthreads(); }
  if (t==0) cntf[a]=(float)sd[0];
}

// ---------------- K/V projection: (NFP x 128) = fe @ W + b ----------------
__global__ __launch_bounds__(256)
void kvproj_kern(const float* __restrict__ fe,
                 const float* __restrict__ Wk, const float* __restrict__ bk,
                 const float* __restrict__ Wv, const float* __restrict__ bv,
                 float* __restrict__ Kout, float* __restrict__ Vout){
  __shared__ float As[32][68];
  __shared__ float Bs[32][132];
  const int t=threadIdx.x;
  const int f0=blockIdx.x*64;
  const float* W  = blockIdx.y ? Wv : Wk;
  const float* bb = blockIdx.y ? bv : bk;
  float* Out      = blockIdx.y ? Vout : Kout;
  float acc[4][8];
  #pragma unroll
  for(int i=0;i<4;i++){ for(int j=0;j<8;j++) acc[i][j]=0.f; }
  for (int kc=0;kc<128;kc+=32){
    { const int floc=t>>2, koff=(t&3)*8; const int f=f0+floc;
      if (f<NF){
        const float* src=fe+((size_t)f<<7)+kc+koff;
        float4 a=*(const float4*)src, b=*(const float4*)(src+4);
        As[koff+0][floc]=a.x; As[koff+1][floc]=a.y; As[koff+2][floc]=a.z; As[koff+3][floc]=a.w;
        As[koff+4][floc]=b.x; As[koff+5][floc]=b.y; As[koff+6][floc]=b.z; As[koff+7][floc]=b.w;
      } else { for(int i=0;i<8;i++) As[koff+i][floc]=0.f; } }
    { const int kk=t>>3, coff=(t&7)*16;
      const float* src=W+((size_t)(kc+kk)<<7)+coff;
      float4 a=*(const float4*)src, b=*(const float4*)(src+4), c=*(const float4*)(src+8), d=*(const float4*)(src+12);
      Bs[kk][coff+0]=a.x;Bs[kk][coff+1]=a.y;Bs[kk][coff+2]=a.z;Bs[kk][coff+3]=a.w;
      Bs[kk][coff+4]=b.x;Bs[kk][coff+5]=b.y;Bs[kk][coff+6]=b.z;Bs[kk][coff+7]=b.w;
      Bs[kk][coff+8]=c.x;Bs[kk][coff+9]=c.y;Bs[kk][coff+10]=c.z;Bs[kk][coff+11]=c.w;
      Bs[kk][coff+12]=d.x;Bs[kk][coff+13]=d.y;Bs[kk][coff+14]=d.z;Bs[kk][coff+15]=d.w; }
    __syncthreads();
    const int mloc=(t&15)*4, nloc=(t>>4)*8;
    #pragma unroll
    for (int kk=0;kk<32;kk++){
      const float4 a=*(const float4*)&As[kk][mloc];
      const float4 b0=*(const float4*)&Bs[kk][nloc];
      const float4 b1=*(const float4*)&Bs[kk][nloc+4];
      const float am[4]={a.x,a.y,a.z,a.w};
      const float bn[8]={b0.x,b0.y,b0.z,b0.w,b1.x,b1.y,b1.z,b1.w};
      #pragma unroll
      for(int mi=0;mi<4;mi++){
        #pragma unroll
        for(int ni=0;ni<8;ni++) acc[mi][ni]=fmaf(am[mi],bn[ni],acc[mi][ni]);
      }
    }
    __syncthreads();
  }
  const int mloc=(t&15)*4, nloc=(t>>4)*8;
  #pragma unroll
  for(int mi=0;mi<4;mi++){
    const int f=f0+mloc+mi;
    float o[8];
    #pragma unroll
    for(int ni=0;ni<8;ni++) o[ni]=(f<NF)? (acc[mi][ni]+bb[nloc+ni]) : 0.f;
    float* dst=Out+((size_t)f<<7)+nloc;
    *(float4*)dst     = make_float4(o[0],o[1],o[2],o[3]);
    *(float4*)(dst+4) = make_float4(o[4],o[5],o[6],o[7]);
  }
}

// ---------------- q = h @ Wq + bq ----------------
__global__ __launch_bounds__(128)
void qproj_kern(const float* __restrict__ h, const float* __restrict__ Wq,
                const float* __restrict__ bq, float* __restrict__ q){
  __shared__ float hs[128];
  const int v=blockIdx.x, c=threadIdx.x;
  hs[c]=h[(v<<7)+c];
  __syncthreads();
  float acc=bq[c];
  #pragma unroll 8
  for (int k=0;k<128;k++) acc=fmaf(hs[k],Wq[(k<<7)+c],acc);
  q[(v<<7)+c]=acc;
}

// ---------------- scores: P = exp(scale*q.K^T) (bf16), + row sums ----------------
template<int FINAL>
__global__ __launch_bounds__(256)
void scores_kern(const float* __restrict__ qb, const float* __restrict__ Kb,
                 const float* __restrict__ gum, unsigned short* __restrict__ Pb,
                 float* __restrict__ accg){
  __shared__ float As[32][68];
  __shared__ float Bs[32][132];
  __shared__ float Zs[64], Zls[64], Yps[64], Yls[64];
  const int t=threadIdx.x;
  const int f0=blockIdx.x*128;
  const int v0=blockIdx.y*64;
  float acc[4][8];
  #pragma unroll
  for(int i=0;i<4;i++){ for(int j=0;j<8;j++) acc[i][j]=0.f; }
  if (t<64){ Zs[t]=0.f; if(FINAL){ Zls[t]=0.f; Yps[t]=0.f; Yls[t]=0.f; } }
  for (int kc=0;kc<128;kc+=32){
    { const int vloc=t>>2, koff=(t&3)*8;
      const float* src=qb+((size_t)(v0+vloc)<<7)+kc+koff;
      float4 a=*(const float4*)src, b=*(const float4*)(src+4);
      As[koff+0][vloc]=a.x; As[koff+1][vloc]=a.y; As[koff+2][vloc]=a.z; As[koff+3][vloc]=a.w;
      As[koff+4][vloc]=b.x; As[koff+5][vloc]=b.y; As[koff+6][vloc]=b.z; As[koff+7][vloc]=b.w; }
    { const int floc=t>>1, koff=(t&1)*16; const int f=f0+floc;
      if (f<NF){
        const float* src=Kb+((size_t)f<<7)+kc+koff;
        float4 a=*(const float4*)src, b=*(const float4*)(src+4), c=*(const float4*)(src+8), d=*(const float4*)(src+12);
        Bs[koff+0][floc]=a.x;Bs[koff+1][floc]=a.y;Bs[koff+2][floc]=a.z;Bs[koff+3][floc]=a.w;
        Bs[koff+4][floc]=b.x;Bs[koff+5][floc]=b.y;Bs[koff+6][floc]=b.z;Bs[koff+7][floc]=b.w;
        Bs[koff+8][floc]=c.x;Bs[koff+9][floc]=c.y;Bs[koff+10][floc]=c.z;Bs[koff+11][floc]=c.w;
        Bs[koff+12][floc]=d.x;Bs[koff+13][floc]=d.y;Bs[koff+14][floc]=d.z;Bs[koff+15][floc]=d.w;
      } else { for(int i=0;i<16;i++) Bs[koff+i][floc]=0.f; } }
    __syncthreads();
    const int mloc=(t&15)*4, nloc=(t>>4)*8;
    #pragma unroll
    for (int kk=0;kk<32;kk++){
      const float4 a=*(const float4*)&As[kk][mloc];
      const float4 b0=*(const float4*)&Bs[kk][nloc];
      const float4 b1=*(const float4*)&Bs[kk][nloc+4];
      const float am[4]={a.x,a.y,a.z,a.w};
      const float bn[8]={b0.x,b0.y,b0.z,b0.w,b1.x,b1.y,b1.z,b1.w};
      #pragma unroll
      for(int mi=0;mi<4;mi++){
        #pragma unroll
        for(int ni=0;ni<8;ni++) acc[mi][ni]=fmaf(am[mi],bn[ni],acc[mi][ni]);
      }
    }
    __syncthreads();
  }
  const int mloc=(t&15)*4, nloc=(t>>4)*8;
  #pragma unroll
  for(int mi=0;mi<4;mi++){
    const int v=v0+mloc+mi;
    float zp=0.f, zl=0.f, yp=0.f, yl=0.f;
    float uu[8];
    if (FINAL){
      const int fbase=f0+nloc;
      if (fbase+8<=NF){
        const float* gsrc=gum+(size_t)v*NF+fbase;
        float4 g0=*(const float4*)gsrc, g1=*(const float4*)(gsrc+4);
        uu[0]=g0.x;uu[1]=g0.y;uu[2]=g0.z;uu[3]=g0.w;uu[4]=g1.x;uu[5]=g1.y;uu[6]=g1.z;uu[7]=g1.w;
      } else {
        for(int i=0;i<8;i++){ int f=fbase+i; uu[i]=(f<NF)? gum[(size_t)v*NF+f] : 0.5f; }
      }
    }
    unsigned short pr[8];
    #pragma unroll
    for(int ni=0;ni<8;ni++){
      const int f=f0+nloc+ni;
      const float s=acc[mi][ni]*SCALE_QK;
      float pv_=0.f;
      if (f<NF){
        const float ep=__expf(s);
        if (FINAL){
          const float g=-__logf(-__logf(uu[ni]));
          const float el=__expf(2.0f*(s+g));
          pv_=el; zl+=el; yl+=el*s; zp+=ep; yp+=ep*s;
        } else { pv_=ep; zp+=ep; }
      }
      pr[ni]=f2bf(pv_);
    }
    uint4 pk;
    pk.x=(unsigned)pr[0]|((unsigned)pr[1]<<16);
    pk.y=(unsigned)pr[2]|((unsigned)pr[3]<<16);
    pk.z=(unsigned)pr[4]|((unsigned)pr[5]<<16);
    pk.w=(unsigned)pr[6]|((unsigned)pr[7]<<16);
    *(uint4*)(Pb+(size_t)v*NFP+f0+nloc)=pk;
    atomicAdd(&Zs[mloc+mi],zp);
    if (FINAL){ atomicAdd(&Zls[mloc+mi],zl); atomicAdd(&Yps[mloc+mi],yp); atomicAdd(&Yls[mloc+mi],yl); }
  }
  __syncthreads();
  if (t<64){
    atomicAdd(&accg[v0+t],Zs[t]);
    if (FINAL){
      atomicAdd(&accg[1024+v0+t],Zls[t]);
      atomicAdd(&accg[2048+v0+t],Yps[t]);
      atomicAdd(&accg[3072+v0+t],Yls[t]);
    }
  }
}

// ---------------- PV: partial[slice] = P_slice @ V_slice ----------------
__global__ __launch_bounds__(256)
void pv_kern(const unsigned short* __restrict__ Pb, const float* __restrict__ Vb,
             float* __restrict__ part){
  __shared__ float As[32][68];
  __shared__ float Bs[32][132];
  const int t=threadIdx.x;
  const int slice=blockIdx.x;
  const int v0=blockIdx.y*64;
  const int fbeg=slice*2048;
  const int fend=min(fbeg+2048,(int)NFP);
  float acc[4][8];
  #pragma unroll
  for(int i=0;i<4;i++){ for(int j=0;j<8;j++) acc[i][j]=0.f; }
  for (int fc=fbeg; fc<fend; fc+=32){
    { const int vloc=t>>2, koff=(t&3)*8;
      const unsigned short* src=Pb+(size_t)(v0+vloc)*NFP+fc+koff;
      uint4 r=*(const uint4*)src;
      As[koff+0][vloc]=bflo(r.x); As[koff+1][vloc]=bfhi(r.x);
      As[koff+2][vloc]=bflo(r.y); As[koff+3][vloc]=bfhi(r.y);
      As[koff+4][vloc]=bflo(r.z); As[koff+5][vloc]=bfhi(r.z);
      As[koff+6][vloc]=bflo(r.w); As[koff+7][vloc]=bfhi(r.w); }
    { const int kk=t>>3, doff=(t&7)*16;
      const float* src=Vb+((size_t)(fc+kk)<<7)+doff;
      float4 a=*(const float4*)src, b=*(const float4*)(src+4), c=*(const float4*)(src+8), d=*(const float4*)(src+12);
      Bs[kk][doff+0]=a.x;Bs[kk][doff+1]=a.y;Bs[kk][doff+2]=a.z;Bs[kk][doff+3]=a.w;
      Bs[kk][doff+4]=b.x;Bs[kk][doff+5]=b.y;Bs[kk][doff+6]=b.z;Bs[kk][doff+7]=b.w;
      Bs[kk][doff+8]=c.x;Bs[kk][doff+9]=c.y;Bs[kk][doff+10]=c.z;Bs[kk][doff+11]=c.w;
      Bs[kk][doff+12]=d.x;Bs[kk][doff+13]=d.y;Bs[kk][doff+14]=d.z;Bs[kk][doff+15]=d.w; }
    __syncthreads();
    const int mloc=(t&15)*4, nloc=(t>>4)*8;
    #pragma unroll
    for (int kk=0;kk<32;kk++){
      const float4 a=*(const float4*)&As[kk][mloc];
      const float4 b0=*(const float4*)&Bs[kk][nloc];
      const float4 b1=*(const float4*)&Bs[kk][nloc+4];
      const float am[4]={a.x,a.y,a.z,a.w};
      const float bn[8]={b0.x,b0.y,b0.z,b0.w,b1.x,b1.y,b1.z,b1.w};
      #pragma unroll
      for(int mi=0;mi<4;mi++){
        #pragma unroll
        for(int ni=0;ni<8;ni++) acc[mi][ni]=fmaf(am[mi],bn[ni],acc[mi][ni]);
      }
    }
    __syncthreads();
  }
  const int mloc=(t&15)*4, nloc=(t>>4)*8;
  #pragma unroll
  for(int mi=0;mi<4;mi++){
    const int v=v0+mloc+mi;
    float* dst=part+(((size_t)slice*NV+v)<<7)+nloc;
    *(float4*)dst     = make_float4(acc[mi][0],acc[mi][1],acc[mi][2],acc[mi][3]);
    *(float4*)(dst+4) = make_float4(acc[mi][4],acc[mi][5],acc[mi][6],acc[mi][7]);
  }
}

// ---------------- main-loop gate update ----------------
__global__ __launch_bounds__(256)
void gate_kern(float* __restrict__ h, const float* __restrict__ part, const float* __restrict__ Z,
               const float* __restrict__ Wm1, const float* __restrict__ bm1,
               const float* __restrict__ Wm2, const float* __restrict__ bm2){
  const int t=threadIdx.x, w=t>>6, lane=t&63;
  const int v=(blockIdx.x<<2)+w;
  const float h0=h[(v<<7)+lane], h1=h[(v<<7)+64+lane];
  const float zr=1.0f/Z[v];
  float c0=0.f,c1=0.f;
  for (int s=0;s<NSLICE;s++){
    c0+=part[(((size_t)s*NV+v)<<7)+lane];
    c1+=part[(((size_t)s*NV+v)<<7)+64+lane];
  }
  c0*=zr; c1*=zr;
  float y0=bm1[lane], y1=bm1[64+lane];
  for (int k=0;k<64;k++){ const float a=__shfl(h0,k); y0=fmaf(a,Wm1[(k<<7)+lane],y0);      y1=fmaf(a,Wm1[(k<<7)+64+lane],y1); }
  for (int k=0;k<64;k++){ const float a=__shfl(h1,k); y0=fmaf(a,Wm1[((64+k)<<7)+lane],y0); y1=fmaf(a,Wm1[((64+k)<<7)+64+lane],y1); }
  for (int k=0;k<64;k++){ const float a=__shfl(c0,k); y0=fmaf(a,Wm1[((128+k)<<7)+lane],y0);y1=fmaf(a,Wm1[((128+k)<<7)+64+lane],y1); }
  for (int k=0;k<64;k++){ const float a=__shfl(c1,k); y0=fmaf(a,Wm1[((192+k)<<7)+lane],y0);y1=fmaf(a,Wm1[((192+k)<<7)+64+lane],y1); }
  y0=geluf(y0); y1=geluf(y1);
  float z0=bm2[lane], z1=bm2[64+lane];
  for (int k=0;k<64;k++){ const float a=__shfl(y0,k); z0=fmaf(a,Wm2[(k<<7)+lane],z0);      z1=fmaf(a,Wm2[(k<<7)+64+lane],z1); }
  for (int k=0;k<64;k++){ const float a=__shfl(y1,k); z0=fmaf(a,Wm2[((64+k)<<7)+lane],z0); z1=fmaf(a,Wm2[((64+k)<<7)+64+lane],z1); }
  const float g0=sigmf(z0), g1=sigmf(z1);
  h[(v<<7)+lane]   = fmaf(g0,c0-h0,h0);
  h[(v<<7)+64+lane]= fmaf(g1,c1-h1,h1);
}

// ---------------- cooc scan (persistent, 64 blocks x 1024 thr, RELAXED grid barrier per atom) ----
__global__ __launch_bounds__(1024,4)
void cooc_kern(float* __restrict__ h, const int* __restrict__ cm, const float* __restrict__ cntf,
               const float* __restrict__ Wc1, const float* __restrict__ bc1,
               const float* __restrict__ Wc2, const float* __restrict__ bc2,
               float* __restrict__ bufs, unsigned* __restrict__ ctr){
  __shared__ unsigned W1s[128*64];   // bf16 pairs (c, c+64), Wc1 rows 0..127 (h-part)
  __shared__ unsigned W2s[104*64];   // bf16 pairs, Wc2 rows 0..103 (rest from global)
  __shared__ float ypart[1024];      // 8 k-segments x 128 outputs for avg@Wc1
  __shared__ float avgs[128];
  __shared__ float yavs[128];
  __shared__ float seedb[128];
  __shared__ int   anyf;
  const int t=threadIdx.x, w=t>>6, lane=t&63;
  const int v=(blockIdx.x<<4)+w;
  const int stripe=blockIdx.x&7;
  for (int i=t;i<128*64;i+=1024){ const int k=i>>6,l=i&63;
    W1s[i]=(unsigned)f2bf(Wc1[(k<<7)+l])|(((unsigned)f2bf(Wc1[(k<<7)+64+l]))<<16); }
  for (int i=t;i<104*64;i+=1024){ const int k=i>>6,l=i&63;
    W2s[i]=(unsigned)f2bf(Wc2[(k<<7)+l])|(((unsigned)f2bf(Wc2[(k<<7)+64+l]))<<16); }
  float h0=h[(v<<7)+lane], h1=h[(v<<7)+64+lane];
  const float b10=bc1[lane], b11=bc1[64+lane];
  const float b20=bc2[lane], b21=bc2[64+lane];
  // ---- seed atom 0 (bufs pre-zeroed by host memset) ----
  if (t<128) seedb[t]=0.f;
  if (t==0) anyf=0;
  __syncthreads();
  if (cm[v]!=0){ atomicAdd(&seedb[lane],h0); atomicAdd(&seedb[64+lane],h1); if(lane==0) anyf=1; }
  __syncthreads();
  if (anyf && t<128) atomicAdd(&bufs[(stripe<<7)+t],seedb[t]);
  unsigned tgt=gridDim.x;
  gridbar(ctr,tgt); tgt+=gridDim.x;
  for (int a=0;a<NA;a++){
    const int cur=a%3, nxt=(a+1)%3, zz=(a+2)%3;
    const float cf=cntf[a];
    // ---- read striped sum -> avgs ----
    if (t<128){
      float s=0.f;
      #pragma unroll
      for (int sp=0;sp<8;sp++)
        s+=__hip_atomic_load(&bufs[(cur<<10)+(sp<<7)+t],__ATOMIC_RELAXED,__HIP_MEMORY_SCOPE_AGENT);
      avgs[t]=s/fmaxf(cf,1.0f);
    }
    if (blockIdx.x==0)
      __hip_atomic_store(&bufs[(zz<<10)+t],0.0f,__ATOMIC_RELAXED,__HIP_MEMORY_SCOPE_AGENT);
    __syncthreads();
    // ---- yavs = avgs @ Wc1[128:256,:]  (split over 8 k-segments, all 16 waves) ----
    { const int seg=t>>7, ok=t&127;
      const int kb=seg<<4;
      float s=0.f;
      #pragma unroll
      for (int j=0;j<16;j++) s=fmaf(avgs[kb+j],Wc1[((128+kb+j)<<7)+ok],s);
      ypart[(seg<<7)+ok]=s; }
    __syncthreads();
    if (t<128){
      float s=0.f;
      #pragma unroll
      for (int seg=0;seg<8;seg++) s+=ypart[(seg<<7)+t];
      yavs[t]=s;
    } else if (t<256) seedb[t-128]=0.f;
    else if (t==256) anyf=0;
    __syncthreads();
    // ---- gate update (1 var per wave) ----
    const bool act=(cm[a*NV+v]!=0)&&(cf>=2.0f);
    if (act){
      const float av0=avgs[lane], av1=avgs[64+lane];
      float y0=b10+yavs[lane], y1=b11+yavs[64+lane];
      #pragma unroll 8
      for (int k=0;k<64;k++){ const float hk=__shfl(h0,k); const unsigned wp=W1s[(k<<6)+lane];
        y0=fmaf(hk,bflo(wp),y0); y1=fmaf(hk,bfhi(wp),y1); }
      #pragma unroll 8
      for (int k=0;k<64;k++){ const float hk=__shfl(h1,k); const unsigned wp=W1s[((64+k)<<6)+lane];
        y0=fmaf(hk,bflo(wp),y0); y1=fmaf(hk,bfhi(wp),y1); }
      y0=geluf(y0); y1=geluf(y1);
      float z0=b20, z1=b21;
      #pragma unroll 8
      for (int k=0;k<64;k++){ const float yk=__shfl(y0,k); const unsigned wp=W2s[(k<<6)+lane];
        z0=fmaf(yk,bflo(wp),z0); z1=fmaf(yk,bfhi(wp),z1); }
      #pragma unroll 8
      for (int k=0;k<40;k++){ const float yk=__shfl(y1,k); const unsigned wp=W2s[((64+k)<<6)+lane];
        z0=fmaf(yk,bflo(wp),z0); z1=fmaf(yk,bfhi(wp),z1); }
      for (int k=40;k<64;k++){ const float yk=__shfl(y1,k);
        z0=fmaf(yk,Wc2[((64+k)<<7)+lane],z0); z1=fmaf(yk,Wc2[((64+k)<<7)+64+lane],z1); }
      const float g0=sigmf(z0), g1=sigmf(z1);
      h0=fmaf(g0,av0-h0,h0); h1=fmaf(g1,av1-h1,h1);
    }
    // ---- block-aggregated seed for atom a+1 ----
    if (a<NA-1){
      if (cm[(a+1)*NV+v]!=0){
        atomicAdd(&seedb[lane],h0); atomicAdd(&seedb[64+lane],h1);
        if (lane==0) anyf=1;
      }
      __syncthreads();
      if (anyf && t<128)
        atomicAdd(&bufs[(nxt<<10)+(stripe<<7)+t],seedb[t]);
      gridbar(ctr,tgt); tgt+=gridDim.x;
    }
  }
  h[(v<<7)+lane]=h0; h[(v<<7)+64+lane]=h1;
}

// ---------------- final write-out ----------------
__global__ __launch_bounds__(256)
void writeout_kern(const float* __restrict__ accg, const float* __restrict__ part,
                   float* __restrict__ out){
  const int b=blockIdx.x, t=threadIdx.x;
  const int v0=b*16;
  for (int i=t;i<16*128;i+=256){
    const int v=v0+(i>>7), d=i&127;
    float s=0.f;
    for (int sl=0;sl<NSLICE;sl++) s+=part[(((size_t)sl*NV+v)<<7)+d];
    out[1+((size_t)v<<7)+d]=s/accg[1024+v];
  }
  __shared__ float es[16], hsv[16];
  if (t<16){
    const int v=v0+t;
    const float Zp=accg[v], Zl=accg[1024+v], Yp=accg[2048+v], Yl=accg[3072+v];
    es[t]=-Yl/Zl;
    hsv[t]=-(Yp/Zp-logf(Zp));
  }
  __syncthreads();
  if (t==0){
    float a=0.f,c=0.f;
    for(int i=0;i<16;i++){ a+=es[i]; c+=hsv[i]; }
    atomicAdd(&out[0],a);
    atomicAdd(&out[1+(size_t)NV*128],c);
  }
}

// ---------------- host ----------------
extern "C" void kernel_launch(void* const* d_in, const int* in_sizes, int n_in,
                              void* d_out, int out_size, void* d_ws, size_t ws_size,
                              hipStream_t stream){
  (void)in_sizes; (void)n_in; (void)ws_size;
  const float* fe =(const float*)d_in[0];
  const float* vi =(const float*)d_in[1];
  const int*   cm =(const int*)  d_in[2];
  const float* gum=(const float*)d_in[3];
  const float* Wq =(const float*)d_in[4];  const float* bq =(const float*)d_in[5];
  const float* Wk =(const float*)d_in[6];  const float* bk =(const float*)d_in[7];
  const float* Wv =(const float*)d_in[8];  const float* bv =(const float*)d_in[9];
  const float* Wm1=(const float*)d_in[10]; const float* bm1=(const float*)d_in[11];
  const float* Wm2=(const float*)d_in[12]; const float* bm2=(const float*)d_in[13];
  const float* Wc1=(const float*)d_in[14]; const float* bc1=(const float*)d_in[15];
  const float* Wc2=(const float*)d_in[16]; const float* bc2=(const float*)d_in[17];
  float* out=(float*)d_out;
  char* w8=(char*)d_ws;
  float* Kb=(float*)(w8+OFF_K);
  float* Vb=(float*)(w8+OFF_V);
  unsigned short* Pb=(unsigned short*)(w8+OFF_P);
  float* hb=(float*)(w8+OFF_H);
  float* qb=(float*)(w8+OFF_Q);
  float* part=(float*)(w8+OFF_PART);
  float* accb=(float*)(w8+OFF_ACC);
  float* avgb=accb+4096;
  float* cntf=(float*)(w8+OFF_CNT);
  unsigned* ctrs=(unsigned*)(w8+OFF_CTR);

  hipMemsetAsync(out,0,(size_t)out_size*4,stream);
  hipMemsetAsync(ctrs,0,64,stream);
  hipMemcpyAsync(hb,vi,(size_t)NV*128*4,hipMemcpyDeviceToDevice,stream);
  cnt_kern<<<NA,256,0,stream>>>(cm,cntf);
  kvproj_kern<<<dim3(NFP/64,2),256,0,stream>>>(fe,Wk,bk,Wv,bv,Kb,Vb);

  for (int it=0; it<3; it++){
    hipMemsetAsync(accb,0,28672,stream);
    qproj_kern<<<NV,128,0,stream>>>(hb,Wq,bq,qb);
    scores_kern<0><<<dim3(NFP/128,16),256,0,stream>>>(qb,Kb,nullptr,Pb,accb);
    pv_kern<<<dim3(NSLICE,16),256,0,stream>>>(Pb,Vb,part);
    gate_kern<<<NV/4,256,0,stream>>>(hb,part,accb,Wm1,bm1,Wm2,bm2);
    cooc_kern<<<64,1024,0,stream>>>(hb,cm,cntf,Wc1,bc1,Wc2,bc2,avgb,ctrs+it);
  }

  hipMemsetAsync(accb,0,28672,stream);
  qproj_kern<<<NV,128,0,stream>>>(hb,Wq,bq,qb);
  scores_kern<1><<<dim3(NFP/128,16),256,0,stream>>>(qb,Kb,gum,Pb,accb);
  pv_kern<<<dim3(NSLICE,16),256,0,stream>>>(Pb,Vb,part);
  writeout_kern<<<64,256,0,stream>>>(accb,part,out);
}